// Round 2
// baseline (1574.176 us; speedup 1.0000x reference)
//
#include <hip/hip_runtime.h>
#include <hip/hip_bf16.h>

// Problem constants
#define NTOK 8192          // B*S
#define E 1024
#define NS 6               // state count
#define MBIG (NTOK * NS)   // 49152 rows for QKV / Wo GEMMs
#define NSE ((long)NTOK * E)

typedef short short8 __attribute__((ext_vector_type(8)));   // 8 bf16 in 4 VGPRs
typedef float f32x4 __attribute__((ext_vector_type(4)));

#define TM 128
#define TN 128
#define BK 64

// ---------------------------------------------------------------------------
// f32 -> bf16 conversion (weights), n multiple of 4
__global__ __launch_bounds__(256) void cvt_w(
    const float* __restrict__ src, __hip_bfloat16* __restrict__ dst, int n)
{
    const int i = (blockIdx.x * 256 + threadIdx.x) * 4;
    if (i >= n) return;
    const float4 v = *(const float4*)(src + i);
    union { __hip_bfloat16 h[4]; unsigned long long u; } pk;
    pk.h[0] = (__hip_bfloat16)v.x;
    pk.h[1] = (__hip_bfloat16)v.y;
    pk.h[2] = (__hip_bfloat16)v.z;
    pk.h[3] = (__hip_bfloat16)v.w;
    *(unsigned long long*)(dst + i) = pk.u;
}

// ---------------------------------------------------------------------------
// C[M x 1024] = A_f32[M x 1024] @ Wb^T + bias, A converted to bf16 on staging.
// Wb (bf16, 1024x1024 row-major, row j = weights of output col j).
__global__ __launch_bounds__(256) void gemm_a32_bt(
    const float* __restrict__ A,
    const __hip_bfloat16* __restrict__ Wb,
    const float* __restrict__ bias,
    __hip_bfloat16* __restrict__ C)
{
    __shared__ __hip_bfloat16 lA[TM * BK] __attribute__((aligned(16)));
    __shared__ __hip_bfloat16 lB[TN * BK] __attribute__((aligned(16)));

    const int tid  = threadIdx.x;
    const int wave = tid >> 6;
    const int lane = tid & 63;
    const int quad = lane >> 4;
    const int mrow = lane & 15;
    const int wr = wave >> 1;
    const int wc = wave & 1;

    const long m0 = (long)blockIdx.x * TM;
    const int  n0 = blockIdx.y * TN;

    // B async staging geometry (1KB per wave-instr = 8 rows of 64 bf16)
    const int srow = lane >> 3;
    const int scol = (lane & 7) * 8;

    f32x4 acc[4][4] = {};

    for (int k0 = 0; k0 < 1024; k0 += BK) {
        __syncthreads();   // previous compute done before LDS overwrite
        // B: async global->LDS (bf16)
#pragma unroll
        for (int it = 0; it < 4; ++it) {
            const int chunk = it * 4 + wave;          // 0..15
            const int row   = chunk * 8 + srow;       // 0..127
            const __hip_bfloat16* gb = Wb + (long)(n0 + row) * 1024 + k0 + scol;
            __hip_bfloat16* lb = lB + row * BK + scol;
            __builtin_amdgcn_global_load_lds((const __attribute__((address_space(1))) void*)gb,
                                             (__attribute__((address_space(3))) void*)lb, 16, 0, 0);
        }
        // A: explicit f32 load -> cvt -> LDS bf16. 128 rows x 64 f32 = 2048 float4.
#pragma unroll
        for (int u = 0; u < 8; ++u) {
            const int c   = u * 256 + tid;   // 0..2047
            const int row = c >> 4;          // 16 float4 per row
            const int c4  = c & 15;
            const float4 av = *(const float4*)(A + (m0 + row) * 1024 + k0 + c4 * 4);
            union { __hip_bfloat16 h[4]; unsigned long long uu; } pk;
            pk.h[0] = (__hip_bfloat16)av.x;
            pk.h[1] = (__hip_bfloat16)av.y;
            pk.h[2] = (__hip_bfloat16)av.z;
            pk.h[3] = (__hip_bfloat16)av.w;
            *(unsigned long long*)(lA + row * BK + c4 * 4) = pk.uu;
        }
        __syncthreads();   // drains vmcnt+lgkmcnt: staged data visible

#pragma unroll
        for (int kk = 0; kk < BK; kk += 32) {
            short8 af[4], bfr[4];
#pragma unroll
            for (int i = 0; i < 4; ++i)
                af[i] = *(const short8*)(lA + (wr * 64 + i * 16 + mrow) * BK + kk + quad * 8);
#pragma unroll
            for (int j = 0; j < 4; ++j)
                bfr[j] = *(const short8*)(lB + (wc * 64 + j * 16 + mrow) * BK + kk + quad * 8);
#pragma unroll
            for (int i = 0; i < 4; ++i)
#pragma unroll
                for (int j = 0; j < 4; ++j)
                    acc[i][j] = __builtin_amdgcn_mfma_f32_16x16x32_bf16(af[i], bfr[j], acc[i][j], 0, 0, 0);
        }
    }

    // epilogue: C/D layout col = lane&15, row = quad*4 + reg
#pragma unroll
    for (int i = 0; i < 4; ++i) {
#pragma unroll
        for (int j = 0; j < 4; ++j) {
            const int col = n0 + wc * 64 + j * 16 + mrow;
            const float bv = bias[col];
#pragma unroll
            for (int r = 0; r < 4; ++r) {
                const long row = m0 + wr * 64 + i * 16 + quad * 4 + r;
                C[row * 1024 + col] = (__hip_bfloat16)(acc[i][j][r] + bv);
            }
        }
    }
}

// ---------------------------------------------------------------------------
// C[M x 1024] = A_bf16[M x 1024] @ Wb^T + bias (all-bf16 staging, m97 style)
__global__ __launch_bounds__(256) void gemm_bt(
    const __hip_bfloat16* __restrict__ A,
    const __hip_bfloat16* __restrict__ Wb,
    const float* __restrict__ bias,
    __hip_bfloat16* __restrict__ C)
{
    __shared__ __hip_bfloat16 lA[TM * BK] __attribute__((aligned(16)));
    __shared__ __hip_bfloat16 lB[TN * BK] __attribute__((aligned(16)));

    const int tid  = threadIdx.x;
    const int wave = tid >> 6;
    const int lane = tid & 63;
    const int quad = lane >> 4;
    const int mrow = lane & 15;
    const int wr = wave >> 1;
    const int wc = wave & 1;

    const long m0 = (long)blockIdx.x * TM;
    const int  n0 = blockIdx.y * TN;

    const int srow = lane >> 3;
    const int scol = (lane & 7) * 8;

    f32x4 acc[4][4] = {};

    for (int k0 = 0; k0 < 1024; k0 += BK) {
        __syncthreads();
#pragma unroll
        for (int it = 0; it < 4; ++it) {
            const int chunk = it * 4 + wave;
            const int row   = chunk * 8 + srow;
            const __hip_bfloat16* ga = A + (m0 + row) * 1024 + k0 + scol;
            const __hip_bfloat16* gb = Wb + (long)(n0 + row) * 1024 + k0 + scol;
            __hip_bfloat16* la = lA + row * BK + scol;
            __hip_bfloat16* lb = lB + row * BK + scol;
            __builtin_amdgcn_global_load_lds((const __attribute__((address_space(1))) void*)ga,
                                             (__attribute__((address_space(3))) void*)la, 16, 0, 0);
            __builtin_amdgcn_global_load_lds((const __attribute__((address_space(1))) void*)gb,
                                             (__attribute__((address_space(3))) void*)lb, 16, 0, 0);
        }
        __syncthreads();

#pragma unroll
        for (int kk = 0; kk < BK; kk += 32) {
            short8 af[4], bfr[4];
#pragma unroll
            for (int i = 0; i < 4; ++i)
                af[i] = *(const short8*)(lA + (wr * 64 + i * 16 + mrow) * BK + kk + quad * 8);
#pragma unroll
            for (int j = 0; j < 4; ++j)
                bfr[j] = *(const short8*)(lB + (wc * 64 + j * 16 + mrow) * BK + kk + quad * 8);
#pragma unroll
            for (int i = 0; i < 4; ++i)
#pragma unroll
                for (int j = 0; j < 4; ++j)
                    acc[i][j] = __builtin_amdgcn_mfma_f32_16x16x32_bf16(af[i], bfr[j], acc[i][j], 0, 0, 0);
        }
    }

#pragma unroll
    for (int i = 0; i < 4; ++i) {
#pragma unroll
        for (int j = 0; j < 4; ++j) {
            const int col = n0 + wc * 64 + j * 16 + mrow;
            const float bv = bias[col];
#pragma unroll
            for (int r = 0; r < 4; ++r) {
                const long row = m0 + wr * 64 + i * 16 + quad * 4 + r;
                C[row * 1024 + col] = (__hip_bfloat16)(acc[i][j][r] + bv);
            }
        }
    }
}

// ---------------------------------------------------------------------------
// Tiny 6x6 attention per (token, head). One wave per (n,h); lane = d in [0,64).
// ctx aliases qb (in-place): each wave reads exactly the range it writes.
__global__ __launch_bounds__(256) void attn6(
    const __hip_bfloat16* qb,
    const __hip_bfloat16* __restrict__ kb,
    const __hip_bfloat16* __restrict__ vb,
    __hip_bfloat16* ctx)
{
    const int wid  = blockIdx.x * 4 + (threadIdx.x >> 6);
    const int lane = threadIdx.x & 63;
    const int n = wid >> 4;
    const int h = wid & 15;
    const long base = (long)n * 1024 + h * 64 + lane;

    float qf[NS], kf[NS], vf[NS];
#pragma unroll
    for (int s = 0; s < NS; ++s) {
        qf[s] = (float)qb[s * NSE + base];
        kf[s] = (float)kb[s * NSE + base];
        vf[s] = (float)vb[s * NSE + base];
    }

    float p[NS][NS];
#pragma unroll
    for (int i = 0; i < NS; ++i)
#pragma unroll
        for (int j = 0; j < NS; ++j) {
            float t = qf[i] * kf[j];
#pragma unroll
            for (int off = 32; off; off >>= 1) t += __shfl_xor(t, off, 64);
            p[i][j] = t * 0.125f;   // 1/sqrt(64)
        }

#pragma unroll
    for (int i = 0; i < NS; ++i) {
        float m = p[i][0];
#pragma unroll
        for (int j = 1; j < NS; ++j) m = fmaxf(m, p[i][j]);
        float sum = 0.f;
#pragma unroll
        for (int j = 0; j < NS; ++j) { p[i][j] = __expf(p[i][j] - m); sum += p[i][j]; }
        const float inv = 1.0f / sum;
        float a = 0.f;
#pragma unroll
        for (int j = 0; j < NS; ++j) a += p[i][j] * vf[j];
        ctx[i * NSE + base] = (__hip_bfloat16)(a * inv);
    }
}

// ---------------------------------------------------------------------------
// enhanced = LN1(wo_out + sf); fused[n] = sum_s softmax(fw)[s] * enhanced[s][n]
__global__ __launch_bounds__(256) void ln1_fuse(
    const __hip_bfloat16* __restrict__ wo_out,   // [6][N][E] bf16
    const float* __restrict__ sf,                // [6][N][E] f32 (input)
    const float* __restrict__ g,
    const float* __restrict__ b,
    const float* __restrict__ fw,                // [6]
    __hip_bfloat16* __restrict__ fused)          // [N][E] bf16
{
    const int n = blockIdx.x, tid = threadIdx.x;
    const int wave = tid >> 6, lane = tid & 63;

    float w[NS];
    float mx = -1e30f;
#pragma unroll
    for (int s = 0; s < NS; ++s) { w[s] = fw[s]; mx = fmaxf(mx, w[s]); }
    float sw = 0.f;
#pragma unroll
    for (int s = 0; s < NS; ++s) { w[s] = __expf(w[s] - mx); sw += w[s]; }
    const float isw = 1.0f / sw;

    float gv[4], bv[4];
#pragma unroll
    for (int c = 0; c < 4; ++c) {
        const int e = c * 256 + tid;
        gv[c] = g[e];
        bv[c] = b[e];
    }

    __shared__ float red[2][4];
    float accf[4] = {0.f, 0.f, 0.f, 0.f};

    for (int s = 0; s < NS; ++s) {
        float x[4];
        float sum = 0.f, sq = 0.f;
#pragma unroll
        for (int c = 0; c < 4; ++c) {
            const long idx = s * NSE + (long)n * 1024 + c * 256 + tid;
            x[c] = (float)wo_out[idx] + sf[idx];
            sum += x[c];
            sq  += x[c] * x[c];
        }
#pragma unroll
        for (int off = 32; off; off >>= 1) {
            sum += __shfl_xor(sum, off, 64);
            sq  += __shfl_xor(sq,  off, 64);
        }
        if (lane == 0) { red[0][wave] = sum; red[1][wave] = sq; }
        __syncthreads();
        sum = red[0][0] + red[0][1] + red[0][2] + red[0][3];
        sq  = red[1][0] + red[1][1] + red[1][2] + red[1][3];
        __syncthreads();
        const float mu   = sum * (1.0f / 1024.0f);
        const float var  = sq * (1.0f / 1024.0f) - mu * mu;
        const float rstd = rsqrtf(var + 1e-5f);
        const float ws_  = w[s] * isw;
#pragma unroll
        for (int c = 0; c < 4; ++c)
            accf[c] += ws_ * ((x[c] - mu) * rstd * gv[c] + bv[c]);
    }
#pragma unroll
    for (int c = 0; c < 4; ++c)
        fused[(long)n * 1024 + c * 256 + tid] = (__hip_bfloat16)accf[c];
}

// ---------------------------------------------------------------------------
// out = LN2(LeakyReLU(hidden)); f32 output
__global__ __launch_bounds__(256) void ln2_out(
    const __hip_bfloat16* __restrict__ hidden,   // [N][1024] bf16 (bias added)
    const float* __restrict__ g,
    const float* __restrict__ b,
    float* __restrict__ out)
{
    const int n = blockIdx.x, tid = threadIdx.x;
    const int wave = tid >> 6, lane = tid & 63;
    __shared__ float red[2][4];

    float x[4];
    float sum = 0.f, sq = 0.f;
#pragma unroll
    for (int c = 0; c < 4; ++c) {
        float t = (float)hidden[(long)n * 1024 + c * 256 + tid];
        t = t >= 0.f ? t : 0.01f * t;     // LeakyReLU(0.01)
        x[c] = t;
        sum += t;
        sq  += t * t;
    }
#pragma unroll
    for (int off = 32; off; off >>= 1) {
        sum += __shfl_xor(sum, off, 64);
        sq  += __shfl_xor(sq,  off, 64);
    }
    if (lane == 0) { red[0][wave] = sum; red[1][wave] = sq; }
    __syncthreads();
    sum = red[0][0] + red[0][1] + red[0][2] + red[0][3];
    sq  = red[1][0] + red[1][1] + red[1][2] + red[1][3];
    const float mu   = sum * (1.0f / 1024.0f);
    const float var  = sq * (1.0f / 1024.0f) - mu * mu;
    const float rstd = rsqrtf(var + 1e-5f);
#pragma unroll
    for (int c = 0; c < 4; ++c) {
        const int e = c * 256 + tid;
        out[(long)n * 1024 + e] = (x[c] - mu) * rstd * g[e] + b[e];
    }
}

// ---------------------------------------------------------------------------
extern "C" void kernel_launch(void* const* d_in, const int* in_sizes, int n_in,
                              void* d_out, int out_size, void* d_ws, size_t ws_size,
                              hipStream_t stream)
{
    const float* SF  = (const float*)d_in[0];   // (6,B,S,E) == [s][n][e], f32
    const float* Wq  = (const float*)d_in[1];
    const float* bq  = (const float*)d_in[2];
    const float* Wk  = (const float*)d_in[3];
    const float* bk  = (const float*)d_in[4];
    const float* Wv  = (const float*)d_in[5];
    const float* bv  = (const float*)d_in[6];
    const float* Wo  = (const float*)d_in[7];
    const float* bo  = (const float*)d_in[8];
    const float* g1  = (const float*)d_in[9];
    const float* b1  = (const float*)d_in[10];
    const float* fw  = (const float*)d_in[11];
    const float* Wf  = (const float*)d_in[12];
    const float* bf_ = (const float*)d_in[13];
    const float* g2  = (const float*)d_in[14];
    const float* b2  = (const float*)d_in[15];
    float* out = (float*)d_out;

    // workspace (bf16): q | k | v | Wqb Wkb Wvb Wob Wfb   (~312 MB total)
    __hip_bfloat16* q   = (__hip_bfloat16*)d_ws;
    __hip_bfloat16* k   = q + (long)MBIG * 1024;
    __hip_bfloat16* v   = k + (long)MBIG * 1024;
    __hip_bfloat16* Wqb = v + (long)MBIG * 1024;
    __hip_bfloat16* Wkb = Wqb + 1024 * 1024;
    __hip_bfloat16* Wvb = Wkb + 1024 * 1024;
    __hip_bfloat16* Wob = Wvb + 1024 * 1024;
    __hip_bfloat16* Wfb = Wob + 1024 * 1024;
    // overlays: fused -> v region (v dead after attn); hidden -> q region
    __hip_bfloat16* fused  = v;
    __hip_bfloat16* hidden = q;

    const dim3 blk(256);
    const dim3 gBig(MBIG / TM, 1024 / TN);   // 384 x 8
    const dim3 gSm(NTOK / TM, 1024 / TN);    // 64 x 8
    const int nW = 1024 * 1024;

    // weight conversions (f32 -> bf16)
    cvt_w<<<nW / 4 / 256, blk, 0, stream>>>(Wq, Wqb, nW);
    cvt_w<<<nW / 4 / 256, blk, 0, stream>>>(Wk, Wkb, nW);
    cvt_w<<<nW / 4 / 256, blk, 0, stream>>>(Wv, Wvb, nW);
    cvt_w<<<nW / 4 / 256, blk, 0, stream>>>(Wo, Wob, nW);
    cvt_w<<<nW / 4 / 256, blk, 0, stream>>>(Wf, Wfb, nW);

    // QKV projections: A = SF (f32) read directly, rows m = s*8192 + n
    gemm_a32_bt<<<gBig, blk, 0, stream>>>(SF, Wqb, bq, q);
    gemm_a32_bt<<<gBig, blk, 0, stream>>>(SF, Wkb, bk, k);
    gemm_a32_bt<<<gBig, blk, 0, stream>>>(SF, Wvb, bv, v);

    // attention: ctx written in-place into q
    attn6<<<NTOK * 16 / 4, blk, 0, stream>>>(q, k, v, q);

    // out = ctx @ Wo^T + bo  -> into k (dead after this consumer chain starts)
    gemm_bt<<<gBig, blk, 0, stream>>>(q, Wob, bo, k);

    // LN1 + residual + weighted fusion -> fused (v region)
    ln1_fuse<<<NTOK, blk, 0, stream>>>(k, SF, g1, b1, fw, fused);

    // hidden = fused @ Wf^T + bf -> q region
    gemm_bt<<<gSm, blk, 0, stream>>>(fused, Wfb, bf_, hidden);

    // LeakyReLU + LN2 -> out (f32)
    ln2_out<<<NTOK, blk, 0, stream>>>(hidden, g2, b2, out);
}

// Round 3
// 1227.703 us; speedup vs baseline: 1.2822x; 1.2822x over previous
//
#include <hip/hip_runtime.h>
#include <hip/hip_bf16.h>

// Problem constants
#define NTOK 8192          // B*S
#define E 1024
#define NS 6               // state count
#define MBIG (NTOK * NS)   // 49152 rows for QKV / Wo GEMMs
#define NSE ((long)NTOK * E)

typedef short short8 __attribute__((ext_vector_type(8)));   // 8 bf16 in 4 VGPRs
typedef float f32x4 __attribute__((ext_vector_type(4)));
typedef unsigned short ushort4v __attribute__((ext_vector_type(4)));

#define TM 128
#define TN 128
#define BK 64

static __device__ __forceinline__ float bf2f(unsigned short u) {
    union { unsigned int i; float f; } c; c.i = ((unsigned int)u) << 16; return c.f;
}

// ---------------------------------------------------------------------------
// fused f32 -> bf16 conversion of the 5 weight matrices (1M elems each)
struct WPtrs { const float* s[5]; __hip_bfloat16* d[5]; };
__global__ __launch_bounds__(256) void cvt5_w(WPtrs p)
{
    const int seg = blockIdx.x >> 10;              // 1024 blocks per matrix
    const int i = ((blockIdx.x & 1023) * 256 + threadIdx.x) * 4;
    const float4 v = *(const float4*)(p.s[seg] + i);
    union { __hip_bfloat16 h[4]; unsigned long long u; } pk;
    pk.h[0] = (__hip_bfloat16)v.x;
    pk.h[1] = (__hip_bfloat16)v.y;
    pk.h[2] = (__hip_bfloat16)v.z;
    pk.h[3] = (__hip_bfloat16)v.w;
    *(unsigned long long*)(p.d[seg] + i) = pk.u;
}

// f32 -> bf16, generic (SF conversion), n multiple of 1024*256*4 handled by grid
__global__ __launch_bounds__(256) void cvt_bulk(
    const float* __restrict__ src, __hip_bfloat16* __restrict__ dst)
{
    const long i = ((long)blockIdx.x * 256 + threadIdx.x) * 4;
    const float4 v = *(const float4*)(src + i);
    union { __hip_bfloat16 h[4]; unsigned long long u; } pk;
    pk.h[0] = (__hip_bfloat16)v.x;
    pk.h[1] = (__hip_bfloat16)v.y;
    pk.h[2] = (__hip_bfloat16)v.z;
    pk.h[3] = (__hip_bfloat16)v.w;
    *(unsigned long long*)(dst + i) = pk.u;
}

// ---------------------------------------------------------------------------
// C[M x 1024] = A_bf16 @ Wb^T + bias (pure async staging, m97 style)
// grid = (8, Mtiles): consecutive blocks share the A m-tile (L2 locality)
__global__ __launch_bounds__(256) void gemm_bt(
    const __hip_bfloat16* __restrict__ A,
    const __hip_bfloat16* __restrict__ Wb,
    const float* __restrict__ bias,
    __hip_bfloat16* __restrict__ C)
{
    __shared__ __hip_bfloat16 lA[TM * BK] __attribute__((aligned(16)));
    __shared__ __hip_bfloat16 lB[TN * BK] __attribute__((aligned(16)));

    const int tid  = threadIdx.x;
    const int wave = tid >> 6;
    const int lane = tid & 63;
    const int quad = lane >> 4;
    const int mrow = lane & 15;
    const int wr = wave >> 1;
    const int wc = wave & 1;

    const int  n0 = blockIdx.x * TN;
    const long m0 = (long)blockIdx.y * TM;

    const int srow = lane >> 3;
    const int scol = (lane & 7) * 8;

    f32x4 acc[4][4] = {};

    for (int k0 = 0; k0 < 1024; k0 += BK) {
        __syncthreads();
#pragma unroll
        for (int it = 0; it < 4; ++it) {
            const int chunk = it * 4 + wave;
            const int row   = chunk * 8 + srow;
            const __hip_bfloat16* ga = A + (m0 + row) * 1024 + k0 + scol;
            const __hip_bfloat16* gb = Wb + (long)(n0 + row) * 1024 + k0 + scol;
            __hip_bfloat16* la = lA + row * BK + scol;
            __hip_bfloat16* lb = lB + row * BK + scol;
            __builtin_amdgcn_global_load_lds((const __attribute__((address_space(1))) void*)ga,
                                             (__attribute__((address_space(3))) void*)la, 16, 0, 0);
            __builtin_amdgcn_global_load_lds((const __attribute__((address_space(1))) void*)gb,
                                             (__attribute__((address_space(3))) void*)lb, 16, 0, 0);
        }
        __syncthreads();

#pragma unroll
        for (int kk = 0; kk < BK; kk += 32) {
            short8 af[4], bfr[4];
#pragma unroll
            for (int i = 0; i < 4; ++i)
                af[i] = *(const short8*)(lA + (wr * 64 + i * 16 + mrow) * BK + kk + quad * 8);
#pragma unroll
            for (int j = 0; j < 4; ++j)
                bfr[j] = *(const short8*)(lB + (wc * 64 + j * 16 + mrow) * BK + kk + quad * 8);
#pragma unroll
            for (int i = 0; i < 4; ++i)
#pragma unroll
                for (int j = 0; j < 4; ++j)
                    acc[i][j] = __builtin_amdgcn_mfma_f32_16x16x32_bf16(af[i], bfr[j], acc[i][j], 0, 0, 0);
        }
    }

#pragma unroll
    for (int i = 0; i < 4; ++i) {
#pragma unroll
        for (int j = 0; j < 4; ++j) {
            const int col = n0 + wc * 64 + j * 16 + mrow;
            const float bv = bias[col];
#pragma unroll
            for (int r = 0; r < 4; ++r) {
                const long row = m0 + wr * 64 + i * 16 + quad * 4 + r;
                C[row * 1024 + col] = (__hip_bfloat16)(acc[i][j][r] + bv);
            }
        }
    }
}

// ---------------------------------------------------------------------------
// C = A_f32 @ Wb^T + bias; A converted f32->bf16 during LDS staging.
__global__ __launch_bounds__(256) void gemm_a32_bt(
    const float* __restrict__ A,
    const __hip_bfloat16* __restrict__ Wb,
    const float* __restrict__ bias,
    __hip_bfloat16* __restrict__ C)
{
    __shared__ __hip_bfloat16 lA[TM * BK] __attribute__((aligned(16)));
    __shared__ __hip_bfloat16 lB[TN * BK] __attribute__((aligned(16)));

    const int tid  = threadIdx.x;
    const int wave = tid >> 6;
    const int lane = tid & 63;
    const int quad = lane >> 4;
    const int mrow = lane & 15;
    const int wr = wave >> 1;
    const int wc = wave & 1;

    const int  n0 = blockIdx.x * TN;
    const long m0 = (long)blockIdx.y * TM;

    const int srow = lane >> 3;
    const int scol = (lane & 7) * 8;

    f32x4 acc[4][4] = {};

    for (int k0 = 0; k0 < 1024; k0 += BK) {
        __syncthreads();
#pragma unroll
        for (int it = 0; it < 4; ++it) {
            const int chunk = it * 4 + wave;
            const int row   = chunk * 8 + srow;
            const __hip_bfloat16* gb = Wb + (long)(n0 + row) * 1024 + k0 + scol;
            __hip_bfloat16* lb = lB + row * BK + scol;
            __builtin_amdgcn_global_load_lds((const __attribute__((address_space(1))) void*)gb,
                                             (__attribute__((address_space(3))) void*)lb, 16, 0, 0);
        }
#pragma unroll
        for (int u = 0; u < 8; ++u) {
            const int c   = u * 256 + tid;   // 0..2047, 16 float4 per row
            const int row = c >> 4;
            const int c4  = c & 15;
            const float4 av = *(const float4*)(A + (m0 + row) * 1024 + k0 + c4 * 4);
            union { __hip_bfloat16 h[4]; unsigned long long uu; } pk;
            pk.h[0] = (__hip_bfloat16)av.x;
            pk.h[1] = (__hip_bfloat16)av.y;
            pk.h[2] = (__hip_bfloat16)av.z;
            pk.h[3] = (__hip_bfloat16)av.w;
            *(unsigned long long*)(lA + row * BK + c4 * 4) = pk.uu;
        }
        __syncthreads();

#pragma unroll
        for (int kk = 0; kk < BK; kk += 32) {
            short8 af[4], bfr[4];
#pragma unroll
            for (int i = 0; i < 4; ++i)
                af[i] = *(const short8*)(lA + (wr * 64 + i * 16 + mrow) * BK + kk + quad * 8);
#pragma unroll
            for (int j = 0; j < 4; ++j)
                bfr[j] = *(const short8*)(lB + (wc * 64 + j * 16 + mrow) * BK + kk + quad * 8);
#pragma unroll
            for (int i = 0; i < 4; ++i)
#pragma unroll
                for (int j = 0; j < 4; ++j)
                    acc[i][j] = __builtin_amdgcn_mfma_f32_16x16x32_bf16(af[i], bfr[j], acc[i][j], 0, 0, 0);
        }
    }

#pragma unroll
    for (int i = 0; i < 4; ++i) {
#pragma unroll
        for (int j = 0; j < 4; ++j) {
            const int col = n0 + wc * 64 + j * 16 + mrow;
            const float bv = bias[col];
#pragma unroll
            for (int r = 0; r < 4; ++r) {
                const long row = m0 + wr * 64 + i * 16 + quad * 4 + r;
                C[row * 1024 + col] = (__hip_bfloat16)(acc[i][j][r] + bv);
            }
        }
    }
}

// ---------------------------------------------------------------------------
// 6x6 attention. 16 lanes per head (d = 4/lane), 4 heads per wave, 2 tokens/block.
// Butterfly depth 4 (xor 1,2,4,8 stays inside the 16-lane head group).
// ctx written in-place over q: each wave reads exactly the range it writes.
__global__ __launch_bounds__(256) void attn6(
    const __hip_bfloat16* qb,
    const __hip_bfloat16* __restrict__ kb,
    const __hip_bfloat16* __restrict__ vb,
    __hip_bfloat16* ctx)
{
    const int w    = blockIdx.x * 4 + (threadIdx.x >> 6);
    const int lane = threadIdx.x & 63;
    const int n  = w >> 2;          // token
    const int hg = w & 3;           // head group (4 heads)
    const int h  = hg * 4 + (lane >> 4);
    const int sub = lane & 15;      // d-chunk index: d = sub*4 .. sub*4+3
    const long base = (long)n * 1024 + h * 64 + sub * 4;

    float qf[NS][4], kf[NS][4], vf[NS][4];
#pragma unroll
    for (int s = 0; s < NS; ++s) {
        const ushort4v qs = *(const ushort4v*)(qb + s * NSE + base);
        const ushort4v ks = *(const ushort4v*)(kb + s * NSE + base);
        const ushort4v vs = *(const ushort4v*)(vb + s * NSE + base);
#pragma unroll
        for (int c = 0; c < 4; ++c) {
            qf[s][c] = bf2f(qs[c]);
            kf[s][c] = bf2f(ks[c]);
            vf[s][c] = bf2f(vs[c]);
        }
    }

    float p[NS][NS];
#pragma unroll
    for (int i = 0; i < NS; ++i)
#pragma unroll
        for (int j = 0; j < NS; ++j) {
            float t = qf[i][0] * kf[j][0];
            t = fmaf(qf[i][1], kf[j][1], t);
            t = fmaf(qf[i][2], kf[j][2], t);
            t = fmaf(qf[i][3], kf[j][3], t);
            t += __shfl_xor(t, 1, 64);
            t += __shfl_xor(t, 2, 64);
            t += __shfl_xor(t, 4, 64);
            t += __shfl_xor(t, 8, 64);
            p[i][j] = t * 0.125f;   // 1/sqrt(64)
        }

#pragma unroll
    for (int i = 0; i < NS; ++i) {
        float m = p[i][0];
#pragma unroll
        for (int j = 1; j < NS; ++j) m = fmaxf(m, p[i][j]);
        float sum = 0.f;
#pragma unroll
        for (int j = 0; j < NS; ++j) { p[i][j] = __expf(p[i][j] - m); sum += p[i][j]; }
        const float inv = 1.0f / sum;
        float a[4] = {0.f, 0.f, 0.f, 0.f};
#pragma unroll
        for (int j = 0; j < NS; ++j)
#pragma unroll
            for (int c = 0; c < 4; ++c) a[c] = fmaf(p[i][j], vf[j][c], a[c]);
        union { __hip_bfloat16 h4[4]; unsigned long long u; } pk;
#pragma unroll
        for (int c = 0; c < 4; ++c) pk.h4[c] = (__hip_bfloat16)(a[c] * inv);
        *(unsigned long long*)(ctx + i * NSE + base) = pk.u;
    }
}

// ---------------------------------------------------------------------------
// enhanced = LN1(wo_out + sf); fused[n] = sum_s softmax(fw)[s] * enhanced[s][n]
__global__ __launch_bounds__(256) void ln1_fuse(
    const __hip_bfloat16* __restrict__ wo_out,   // [6][N][E] bf16
    const float* __restrict__ sf,                // [6][N][E] f32 (input)
    const float* __restrict__ g,
    const float* __restrict__ b,
    const float* __restrict__ fw,                // [6]
    __hip_bfloat16* __restrict__ fused)          // [N][E] bf16
{
    const int n = blockIdx.x, tid = threadIdx.x;
    const int wave = tid >> 6, lane = tid & 63;

    float w[NS];
    float mx = -1e30f;
#pragma unroll
    for (int s = 0; s < NS; ++s) { w[s] = fw[s]; mx = fmaxf(mx, w[s]); }
    float sw = 0.f;
#pragma unroll
    for (int s = 0; s < NS; ++s) { w[s] = __expf(w[s] - mx); sw += w[s]; }
    const float isw = 1.0f / sw;

    float gv[4], bv[4];
#pragma unroll
    for (int c = 0; c < 4; ++c) {
        const int e = c * 256 + tid;
        gv[c] = g[e];
        bv[c] = b[e];
    }

    __shared__ float red[2][4];
    float accf[4] = {0.f, 0.f, 0.f, 0.f};

    for (int s = 0; s < NS; ++s) {
        float x[4];
        float sum = 0.f, sq = 0.f;
#pragma unroll
        for (int c = 0; c < 4; ++c) {
            const long idx = s * NSE + (long)n * 1024 + c * 256 + tid;
            x[c] = (float)wo_out[idx] + sf[idx];
            sum += x[c];
            sq  += x[c] * x[c];
        }
#pragma unroll
        for (int off = 32; off; off >>= 1) {
            sum += __shfl_xor(sum, off, 64);
            sq  += __shfl_xor(sq,  off, 64);
        }
        if (lane == 0) { red[0][wave] = sum; red[1][wave] = sq; }
        __syncthreads();
        sum = red[0][0] + red[0][1] + red[0][2] + red[0][3];
        sq  = red[1][0] + red[1][1] + red[1][2] + red[1][3];
        __syncthreads();
        const float mu   = sum * (1.0f / 1024.0f);
        const float var  = sq * (1.0f / 1024.0f) - mu * mu;
        const float rstd = rsqrtf(var + 1e-5f);
        const float ws_  = w[s] * isw;
#pragma unroll
        for (int c = 0; c < 4; ++c)
            accf[c] += ws_ * ((x[c] - mu) * rstd * gv[c] + bv[c]);
    }
#pragma unroll
    for (int c = 0; c < 4; ++c)
        fused[(long)n * 1024 + c * 256 + tid] = (__hip_bfloat16)accf[c];
}

// ---------------------------------------------------------------------------
// out = LN2(LeakyReLU(hidden)); f32 output
__global__ __launch_bounds__(256) void ln2_out(
    const __hip_bfloat16* __restrict__ hidden,   // [N][1024] bf16 (bias added)
    const float* __restrict__ g,
    const float* __restrict__ b,
    float* __restrict__ out)
{
    const int n = blockIdx.x, tid = threadIdx.x;
    const int wave = tid >> 6, lane = tid & 63;
    __shared__ float red[2][4];

    float x[4];
    float sum = 0.f, sq = 0.f;
#pragma unroll
    for (int c = 0; c < 4; ++c) {
        float t = (float)hidden[(long)n * 1024 + c * 256 + tid];
        t = t >= 0.f ? t : 0.01f * t;     // LeakyReLU(0.01)
        x[c] = t;
        sum += t;
        sq  += t * t;
    }
#pragma unroll
    for (int off = 32; off; off >>= 1) {
        sum += __shfl_xor(sum, off, 64);
        sq  += __shfl_xor(sq,  off, 64);
    }
    if (lane == 0) { red[0][wave] = sum; red[1][wave] = sq; }
    __syncthreads();
    sum = red[0][0] + red[0][1] + red[0][2] + red[0][3];
    sq  = red[1][0] + red[1][1] + red[1][2] + red[1][3];
    const float mu   = sum * (1.0f / 1024.0f);
    const float var  = sq * (1.0f / 1024.0f) - mu * mu;
    const float rstd = rsqrtf(var + 1e-5f);
#pragma unroll
    for (int c = 0; c < 4; ++c) {
        const int e = c * 256 + tid;
        out[(long)n * 1024 + e] = (x[c] - mu) * rstd * g[e] + b[e];
    }
}

// ---------------------------------------------------------------------------
extern "C" void kernel_launch(void* const* d_in, const int* in_sizes, int n_in,
                              void* d_out, int out_size, void* d_ws, size_t ws_size,
                              hipStream_t stream)
{
    const float* SF  = (const float*)d_in[0];   // (6,B,S,E), f32
    const float* Wq  = (const float*)d_in[1];
    const float* bq  = (const float*)d_in[2];
    const float* Wk  = (const float*)d_in[3];
    const float* bk  = (const float*)d_in[4];
    const float* Wv  = (const float*)d_in[5];
    const float* bv  = (const float*)d_in[6];
    const float* Wo  = (const float*)d_in[7];
    const float* bo  = (const float*)d_in[8];
    const float* g1  = (const float*)d_in[9];
    const float* b1  = (const float*)d_in[10];
    const float* fw  = (const float*)d_in[11];
    const float* Wf  = (const float*)d_in[12];
    const float* bf_ = (const float*)d_in[13];
    const float* g2  = (const float*)d_in[14];
    const float* b2  = (const float*)d_in[15];
    float* out = (float*)d_out;

    // ws (bf16 regions, ~312 MB peak — proven safe):
    //  r0: q/ctx -> later hidden       (100.7 MB)
    //  r1: k     -> later wo_out       (100.7 MB)
    //  r2: sfb   -> later v -> fused   (100.7 MB)
    //  weights tail (10 MB)
    __hip_bfloat16* r0  = (__hip_bfloat16*)d_ws;
    __hip_bfloat16* r1  = r0 + (long)MBIG * 1024;
    __hip_bfloat16* r2  = r1 + (long)MBIG * 1024;
    __hip_bfloat16* Wqb = r2 + (long)MBIG * 1024;
    __hip_bfloat16* Wkb = Wqb + 1024 * 1024;
    __hip_bfloat16* Wvb = Wkb + 1024 * 1024;
    __hip_bfloat16* Wob = Wvb + 1024 * 1024;
    __hip_bfloat16* Wfb = Wob + 1024 * 1024;

    const dim3 blk(256);
    const dim3 gBig(8, MBIG / TM);   // n-tiles fastest: A-tile L2 reuse
    const dim3 gSm(8, NTOK / TM);

    // weight conversions (one fused kernel)
    WPtrs wp;
    wp.s[0] = Wq; wp.s[1] = Wk; wp.s[2] = Wv; wp.s[3] = Wo; wp.s[4] = Wf;
    wp.d[0] = Wqb; wp.d[1] = Wkb; wp.d[2] = Wvb; wp.d[3] = Wob; wp.d[4] = Wfb;
    cvt5_w<<<5 * 1024, blk, 0, stream>>>(wp);

    // SF f32 -> bf16 into r2 (49152x1024 elems = 48K blocks)
    cvt_bulk<<<MBIG, blk, 0, stream>>>(SF, r2);

    // Q, K from bf16 sfb (pure async GEMM); V from f32 SF, output OVERWRITES sfb
    gemm_bt<<<gBig, blk, 0, stream>>>(r2, Wqb, bq, r0);        // q
    gemm_bt<<<gBig, blk, 0, stream>>>(r2, Wkb, bk, r1);        // k
    gemm_a32_bt<<<gBig, blk, 0, stream>>>(SF, Wvb, bv, r2);    // v (over sfb)

    // attention: ctx in-place into r0
    attn6<<<NTOK, blk, 0, stream>>>(r0, r1, r2, r0);

    // wo_out = ctx @ Wo^T + bo -> r1 (k dead)
    gemm_bt<<<gBig, blk, 0, stream>>>(r0, Wob, bo, r1);

    // LN1 + residual (f32 SF) + weighted fusion -> fused in r2 (v dead)
    ln1_fuse<<<NTOK, blk, 0, stream>>>(r1, SF, g1, b1, fw, r2);

    // hidden = fused @ Wf^T + bf -> r0 (ctx dead)
    gemm_bt<<<gSm, blk, 0, stream>>>(r2, Wfb, bf_, r0);

    // LeakyReLU + LN2 -> out (f32)
    ln2_out<<<NTOK, blk, 0, stream>>>(r0, g2, b2, out);
}